// Round 2
// baseline (610.577 us; speedup 1.0000x reference)
//
#include <hip/hip_runtime.h>
#include <hip/hip_bf16.h>

#define S_ 128
#define N_ 384
#define CM 256
#define CH 32
#define CZ 128

typedef __attribute__((ext_vector_type(8))) __bf16 bf16x8;
typedef __attribute__((ext_vector_type(4))) float f32x4;

union pack4 { __hip_bfloat16 h[4]; uint2 u; };

// ---- Kernel P: fused weight prep -----------------------------------------
// blocks 0..63  : wt12[64][256] bf16 = [w1|w2]^T
// blocks 64..191: woutT[z][cd] bf16
__global__ __launch_bounds__(256) void k_prep(const float* __restrict__ w1,
                                              const float* __restrict__ w2,
                                              const float* __restrict__ wout,
                                              __hip_bfloat16* __restrict__ wt12,
                                              __hip_bfloat16* __restrict__ woutT)
{
    const int b = blockIdx.x, t = threadIdx.x;
    if (b < 64) {
        const float* w = (b < CH) ? w1 : w2;
        wt12[b * CM + t] = __float2bfloat16(w[(size_t)t * CH + (b & 31)]);
    } else {
        const int z = b - 64;
        for (int cd = t; cd < CH*CH; cd += 256)
            woutT[(size_t)z * (CH*CH) + cd] = __float2bfloat16(wout[(size_t)cd * CZ + z]);
    }
}

// ---- Kernel 1: LayerNorm + dual projection via MFMA (unchanged) ----------
#define LNR 264
__global__ __launch_bounds__(256) void k_lnp(
    const float* __restrict__ m, const float* __restrict__ mask,
    const float* __restrict__ gamma, const float* __restrict__ beta,
    const float* __restrict__ b1, const float* __restrict__ b2,
    const __hip_bfloat16* __restrict__ wt12,
    __hip_bfloat16* __restrict__ At, __hip_bfloat16* __restrict__ Bt)
{
    __shared__ __hip_bfloat16 lnS[128 * LNR];
    __shared__ float msk[128];
    const int n0 = blockIdx.x * 16, s0 = blockIdx.y * 8;
    const int t = threadIdx.x, wave = t >> 6, lane = t & 63;
    const int l15 = lane & 15, quad = lane >> 4;

    if (t < 128) msk[t] = mask[(s0 + (t & 7))*N_ + n0 + (t >> 3)];

    float4 g  = ((const float4*)gamma)[lane];
    float4 be = ((const float4*)beta)[lane];
    for (int i = 0; i < 32; ++i) {
        const int row = wave*32 + i;
        const int n = row >> 3, s = row & 7;
        float4 x = ((const float4*)(m + ((size_t)((s0+s)*N_ + n0 + n)) * CM))[lane];
        float sum = x.x + x.y + x.z + x.w;
        float ssq = x.x*x.x + x.y*x.y + x.z*x.z + x.w*x.w;
        #pragma unroll
        for (int off = 32; off >= 1; off >>= 1) {
            sum += __shfl_xor(sum, off, 64);
            ssq += __shfl_xor(ssq, off, 64);
        }
        const float mean = sum * (1.0f/CM);
        const float var  = ssq * (1.0f/CM) - mean*mean;
        const float rstd = rsqrtf(var + 1e-5f);
        pack4 pk;
        pk.h[0] = __float2bfloat16((x.x - mean)*rstd*g.x + be.x);
        pk.h[1] = __float2bfloat16((x.y - mean)*rstd*g.y + be.y);
        pk.h[2] = __float2bfloat16((x.z - mean)*rstd*g.z + be.z);
        pk.h[3] = __float2bfloat16((x.w - mean)*rstd*g.w + be.w);
        *(uint2*)&lnS[row*LNR + lane*4] = pk.u;
    }
    __syncthreads();

    f32x4 acc[2][4];
    const f32x4 z4 = {0.f,0.f,0.f,0.f};
    #pragma unroll
    for (int mt = 0; mt < 2; ++mt)
        #pragma unroll
        for (int nt = 0; nt < 4; ++nt) acc[mt][nt] = z4;

    #pragma unroll
    for (int kk = 0; kk < 8; ++kk) {
        bf16x8 a0 = *(const bf16x8*)&lnS[(wave*32      + l15)*LNR + kk*32 + quad*8];
        bf16x8 a1 = *(const bf16x8*)&lnS[(wave*32 + 16 + l15)*LNR + kk*32 + quad*8];
        #pragma unroll
        for (int nt = 0; nt < 4; ++nt) {
            bf16x8 wv = *(const bf16x8*)&wt12[(size_t)(nt*16 + l15)*CM + kk*32 + quad*8];
            acc[0][nt] = __builtin_amdgcn_mfma_f32_16x16x32_bf16(a0, wv, acc[0][nt], 0,0,0);
            acc[1][nt] = __builtin_amdgcn_mfma_f32_16x16x32_bf16(a1, wv, acc[1][nt], 0,0,0);
        }
    }

    #pragma unroll
    for (int nt = 0; nt < 4; ++nt) {
        const int ncol = nt*16 + l15;
        const int sel = ncol >> 5, c = ncol & 31;
        const float bias = sel ? b2[c] : b1[c];
        __hip_bfloat16* dst = sel ? Bt : At;
        #pragma unroll
        for (int mt = 0; mt < 2; ++mt) {
            const int rowb = wave*32 + mt*16 + quad*4;
            const int n_loc = rowb >> 3, s_loc = rowb & 7;
            pack4 pk;
            #pragma unroll
            for (int r = 0; r < 4; ++r)
                pk.h[r] = __float2bfloat16((acc[mt][nt][r] + bias) * msk[rowb + r]);
            *(uint2*)&dst[((size_t)(n0 + n_loc)*CH + c)*S_ + s0 + s_loc] = pk.u;
        }
    }
}

// ---- Kernel 2: fused MFMA outer-product + w_out GEMM ---------------------
// Block = 8i x 4j (32 p-pairs), 512 thr = 8 waves, grid 48 x 96
// (blockIdx.x = i fastest -> concurrent blocks form a j-band: Bt band +
//  whole At stay L2-resident, the property that kept FETCH at 15 MB).
// LDS O = 32 x 1160 bf16 = 74.2 KB  ->  2 blocks/CU (the R1 occupancy fix,
// without R1's persistent scheduling that killed L2 locality).
// Stage 2: M=256 (8i,32c), N=128 (4j,32d), K=128; wave = M-quarter(mq) x
//   N-half(nh), 4x4 tiles, mfma(B,A), packed uint2 O-writes (c*36 + d).
// Stage 3: wave owns exclusive 16-z slice; wf[32] woutT fragments preloaded
//   per block -> kk-loop is pure LDS+MFMA. RN fused (no k_rnorm launch).
#define OR 1160
__global__ __launch_bounds__(512, 4) void k_opm(
    const __hip_bfloat16* __restrict__ At, const __hip_bfloat16* __restrict__ Bt,
    const float* __restrict__ mask, const __hip_bfloat16* __restrict__ woutT,
    const float* __restrict__ bout, float* __restrict__ out)
{
    __shared__ __hip_bfloat16 O[32 * OR];   // 74.2 KB
    __shared__ float RNl[32];
    const int t = threadIdx.x;
    const int wave = t >> 6, lane = t & 63;
    const int l15 = lane & 15, quad = lane >> 4;
    const int mq = wave & 3, nh = wave >> 2;
    const int i0 = blockIdx.x * 8, j0 = blockIdx.y * 4;

    // per-wave 16-z slice of woutT + bias
    const int zb = wave * 16;
    bf16x8 wf[32];
    #pragma unroll
    for (int kk = 0; kk < 32; ++kk)
        wf[kk] = *(const bf16x8*)&woutT[(size_t)(zb + l15) * (CH*CH) + kk*32 + quad*8];
    const float bz = bout[zb + l15];

    const f32x4 z4 = {0.f,0.f,0.f,0.f};

    // ---- stage 2: acc[nt][mt] = D[(j,d)][(i,c)] ----
    f32x4 acc[4][4];
    #pragma unroll
    for (int nt = 0; nt < 4; ++nt)
        #pragma unroll
        for (int mt = 0; mt < 4; ++mt) acc[nt][mt] = z4;

    int aOff[4], bOff[4];
    #pragma unroll
    for (int mt = 0; mt < 4; ++mt) {
        const int Mrow = mq*64 + mt*16 + l15;       // = i_l*32 + c
        aOff[mt] = ((i0 + (Mrow >> 5)) * CH + (Mrow & 31)) * S_ + quad*8;
    }
    #pragma unroll
    for (int nt = 0; nt < 4; ++nt) {
        const int Ncol = nh*64 + nt*16 + l15;       // = j_l*32 + d
        bOff[nt] = ((j0 + (Ncol >> 5)) * CH + (Ncol & 31)) * S_ + quad*8;
    }

    #pragma unroll
    for (int kk = 0; kk < 4; ++kk) {
        bf16x8 af[4], bfr[4];
        #pragma unroll
        for (int mt = 0; mt < 4; ++mt) af[mt]  = *(const bf16x8*)&At[aOff[mt] + kk*32];
        #pragma unroll
        for (int nt = 0; nt < 4; ++nt) bfr[nt] = *(const bf16x8*)&Bt[bOff[nt] + kk*32];
        #pragma unroll
        for (int nt = 0; nt < 4; ++nt)
            #pragma unroll
            for (int mt = 0; mt < 4; ++mt)
                acc[nt][mt] = __builtin_amdgcn_mfma_f32_16x16x32_bf16(
                    bfr[nt], af[mt], acc[nt][mt], 0, 0, 0);
    }

    // ---- fused RN: p = wave*4+quad owns pair (i0+p>>2, j0+p&3) ----
    {
        const int p = wave*4 + quad;
        const int ic = i0 + (p >> 2), jc = j0 + (p & 3);
        float a = 0.f;
        #pragma unroll
        for (int u = 0; u < 8; ++u) {
            const int s = l15*8 + u;
            a += mask[s*N_ + ic] * mask[s*N_ + jc];
        }
        a += __shfl_xor(a, 1, 64);
        a += __shfl_xor(a, 2, 64);
        a += __shfl_xor(a, 4, 64);
        a += __shfl_xor(a, 8, 64);
        if (l15 == 0) RNl[p] = 1.0f / (a + 1e-3f);
    }

    // ---- O writes: col(l15)->(i_l,c); row(quad,r)->(j_l,d), r = consec d --
    #pragma unroll
    for (int mt = 0; mt < 4; ++mt) {
        const int Mcol = mq*64 + mt*16 + l15;
        const int i_l = Mcol >> 5, c = Mcol & 31;
        #pragma unroll
        for (int nt = 0; nt < 4; ++nt) {
            const int Nrow = nh*64 + nt*16 + quad*4;
            const int j_l = Nrow >> 5, d0 = Nrow & 31;
            const int p = i_l*4 + j_l;              // uniform per (mt,nt)
            pack4 pk;
            #pragma unroll
            for (int r = 0; r < 4; ++r) pk.h[r] = __float2bfloat16(acc[nt][mt][r]);
            *(uint2*)&O[p*OR + c*36 + d0] = pk.u;
        }
    }
    __syncthreads();

    // ---- stage 3: 32p x 16z per wave, K=1024 ----
    f32x4 oacc[2];
    oacc[0] = z4; oacc[1] = z4;
    #pragma unroll
    for (int kk = 0; kk < 32; ++kk) {
        #pragma unroll
        for (int mt2 = 0; mt2 < 2; ++mt2) {
            const int row = mt2*16 + l15;
            bf16x8 a = *(const bf16x8*)&O[row*OR + kk*36 + quad*8];
            oacc[mt2] = __builtin_amdgcn_mfma_f32_16x16x32_bf16(
                a, wf[kk], oacc[mt2], 0, 0, 0);
        }
    }

    // ---- epilogue: col(l15)->z, row(quad,r)->p ----
    #pragma unroll
    for (int mt2 = 0; mt2 < 2; ++mt2) {
        #pragma unroll
        for (int r = 0; r < 4; ++r) {
            const int p = mt2*16 + quad*4 + r;
            const int i = i0 + (p >> 2), j = j0 + (p & 3);
            out[((size_t)(i*N_ + j))*CZ + zb + l15] = (oacc[mt2][r] + bz) * RNl[p];
        }
    }
}

extern "C" void kernel_launch(void* const* d_in, const int* in_sizes, int n_in,
                              void* d_out, int out_size, void* d_ws, size_t ws_size,
                              hipStream_t stream)
{
    const float* m    = (const float*)d_in[0];
    const float* mask = (const float*)d_in[1];
    const float* gam  = (const float*)d_in[2];
    const float* bet  = (const float*)d_in[3];
    const float* w1   = (const float*)d_in[4];
    const float* b1   = (const float*)d_in[5];
    const float* w2   = (const float*)d_in[6];
    const float* b2   = (const float*)d_in[7];
    const float* wout = (const float*)d_in[8];
    const float* bout = (const float*)d_in[9];
    float* out = (float*)d_out;

    __hip_bfloat16* At    = (__hip_bfloat16*)d_ws;                 // [N][CH][S]
    __hip_bfloat16* Bt    = At + (size_t)N_ * CH * S_;             // [N][CH][S]
    __hip_bfloat16* woutT = Bt + (size_t)N_ * CH * S_;             // [CZ][1024]
    __hip_bfloat16* wt12  = woutT + (size_t)CZ * CH * CH;          // [64][256]

    k_prep<<<192, 256, 0, stream>>>(w1, w2, wout, wt12, woutT);
    dim3 gl(24, 16);
    k_lnp<<<gl, 256, 0, stream>>>(m, mask, gam, bet, b1, b2, wt12, At, Bt);
    dim3 grid(N_ / 8, N_ / 4);
    k_opm<<<grid, 512, 0, stream>>>(At, Bt, mask, woutT, bout, out);
}

// Round 3
// 463.295 us; speedup vs baseline: 1.3179x; 1.3179x over previous
//
#include <hip/hip_runtime.h>
#include <hip/hip_bf16.h>

#define S_ 128
#define N_ 384
#define CM 256
#define CH 32
#define CZ 128

typedef __attribute__((ext_vector_type(8))) __bf16 bf16x8;
typedef __attribute__((ext_vector_type(4))) float f32x4;

union pack4 { __hip_bfloat16 h[4]; uint2 u; };

// ---- Kernel P: fused weight prep -----------------------------------------
// blocks 0..63  : wt12[64][256] bf16 = [w1|w2]^T
// blocks 64..191: woutT[z][cd] bf16
__global__ __launch_bounds__(256) void k_prep(const float* __restrict__ w1,
                                              const float* __restrict__ w2,
                                              const float* __restrict__ wout,
                                              __hip_bfloat16* __restrict__ wt12,
                                              __hip_bfloat16* __restrict__ woutT)
{
    const int b = blockIdx.x, t = threadIdx.x;
    if (b < 64) {
        const float* w = (b < CH) ? w1 : w2;
        wt12[b * CM + t] = __float2bfloat16(w[(size_t)t * CH + (b & 31)]);
    } else {
        const int z = b - 64;
        for (int cd = t; cd < CH*CH; cd += 256)
            woutT[(size_t)z * (CH*CH) + cd] = __float2bfloat16(wout[(size_t)cd * CZ + z]);
    }
}

// ---- Kernel 1: LayerNorm + dual projection via MFMA (unchanged) ----------
#define LNR 264
__global__ __launch_bounds__(256) void k_lnp(
    const float* __restrict__ m, const float* __restrict__ mask,
    const float* __restrict__ gamma, const float* __restrict__ beta,
    const float* __restrict__ b1, const float* __restrict__ b2,
    const __hip_bfloat16* __restrict__ wt12,
    __hip_bfloat16* __restrict__ At, __hip_bfloat16* __restrict__ Bt)
{
    __shared__ __hip_bfloat16 lnS[128 * LNR];
    __shared__ float msk[128];
    const int n0 = blockIdx.x * 16, s0 = blockIdx.y * 8;
    const int t = threadIdx.x, wave = t >> 6, lane = t & 63;
    const int l15 = lane & 15, quad = lane >> 4;

    if (t < 128) msk[t] = mask[(s0 + (t & 7))*N_ + n0 + (t >> 3)];

    float4 g  = ((const float4*)gamma)[lane];
    float4 be = ((const float4*)beta)[lane];
    for (int i = 0; i < 32; ++i) {
        const int row = wave*32 + i;
        const int n = row >> 3, s = row & 7;
        float4 x = ((const float4*)(m + ((size_t)((s0+s)*N_ + n0 + n)) * CM))[lane];
        float sum = x.x + x.y + x.z + x.w;
        float ssq = x.x*x.x + x.y*x.y + x.z*x.z + x.w*x.w;
        #pragma unroll
        for (int off = 32; off >= 1; off >>= 1) {
            sum += __shfl_xor(sum, off, 64);
            ssq += __shfl_xor(ssq, off, 64);
        }
        const float mean = sum * (1.0f/CM);
        const float var  = ssq * (1.0f/CM) - mean*mean;
        const float rstd = rsqrtf(var + 1e-5f);
        pack4 pk;
        pk.h[0] = __float2bfloat16((x.x - mean)*rstd*g.x + be.x);
        pk.h[1] = __float2bfloat16((x.y - mean)*rstd*g.y + be.y);
        pk.h[2] = __float2bfloat16((x.z - mean)*rstd*g.z + be.z);
        pk.h[3] = __float2bfloat16((x.w - mean)*rstd*g.w + be.w);
        *(uint2*)&lnS[row*LNR + lane*4] = pk.u;
    }
    __syncthreads();

    f32x4 acc[2][4];
    const f32x4 z4 = {0.f,0.f,0.f,0.f};
    #pragma unroll
    for (int mt = 0; mt < 2; ++mt)
        #pragma unroll
        for (int nt = 0; nt < 4; ++nt) acc[mt][nt] = z4;

    #pragma unroll
    for (int kk = 0; kk < 8; ++kk) {
        bf16x8 a0 = *(const bf16x8*)&lnS[(wave*32      + l15)*LNR + kk*32 + quad*8];
        bf16x8 a1 = *(const bf16x8*)&lnS[(wave*32 + 16 + l15)*LNR + kk*32 + quad*8];
        #pragma unroll
        for (int nt = 0; nt < 4; ++nt) {
            bf16x8 wv = *(const bf16x8*)&wt12[(size_t)(nt*16 + l15)*CM + kk*32 + quad*8];
            acc[0][nt] = __builtin_amdgcn_mfma_f32_16x16x32_bf16(a0, wv, acc[0][nt], 0,0,0);
            acc[1][nt] = __builtin_amdgcn_mfma_f32_16x16x32_bf16(a1, wv, acc[1][nt], 0,0,0);
        }
    }

    #pragma unroll
    for (int nt = 0; nt < 4; ++nt) {
        const int ncol = nt*16 + l15;
        const int sel = ncol >> 5, c = ncol & 31;
        const float bias = sel ? b2[c] : b1[c];
        __hip_bfloat16* dst = sel ? Bt : At;
        #pragma unroll
        for (int mt = 0; mt < 2; ++mt) {
            const int rowb = wave*32 + mt*16 + quad*4;
            const int n_loc = rowb >> 3, s_loc = rowb & 7;
            pack4 pk;
            #pragma unroll
            for (int r = 0; r < 4; ++r)
                pk.h[r] = __float2bfloat16((acc[mt][nt][r] + bias) * msk[rowb + r]);
            *(uint2*)&dst[((size_t)(n0 + n_loc)*CH + c)*S_ + s0 + s_loc] = pk.u;
        }
    }
}

// ---- Kernel 2: fused MFMA outer-product + w_out GEMM ---------------------
// Block = 8i x 4j (32 p-pairs), 512 thr = 8 waves, grid 48 x 96
// (blockIdx.x = i fastest -> concurrent blocks form a j-band; At + Bt band
//  stay L2-resident -> FETCH ~15-40 MB).
// LDS O = 32 x 1160 bf16 = 74.2 KB -> 2 blocks/CU at <=128 VGPR.
// REGISTER BUDGET (the R2 lesson: launch_bounds(512,4) caps unified
// VGPR+AGPR at 128/thread; R2 kept wf[32]=128 live across acc[4][4]=64 and
// spilled 1.6 GB of scratch):
//   stage 2 live: acc 64 + ld transients ~45          < 128
//   stage 3 live: wf chunk 16x4=64 + oacc 8 + ~16     < 128
//   -> wf loaded AFTER the barrier, in TWO 16-frag chunks, oacc carried.
#define OR 1160
__global__ __launch_bounds__(512, 4) void k_opm(
    const __hip_bfloat16* __restrict__ At, const __hip_bfloat16* __restrict__ Bt,
    const float* __restrict__ mask, const __hip_bfloat16* __restrict__ woutT,
    const float* __restrict__ bout, float* __restrict__ out)
{
    __shared__ __hip_bfloat16 O[32 * OR];   // 74.2 KB
    __shared__ float RNl[32];
    const int t = threadIdx.x;
    const int wave = t >> 6, lane = t & 63;
    const int l15 = lane & 15, quad = lane >> 4;
    const int mq = wave & 3, nh = wave >> 2;
    const int i0 = blockIdx.x * 8, j0 = blockIdx.y * 4;
    const int zb = wave * 16;

    const f32x4 z4 = {0.f,0.f,0.f,0.f};

    // ---- stage 2: acc[nt][mt] = D[(j,d)][(i,c)] ----
    f32x4 acc[4][4];
    #pragma unroll
    for (int nt = 0; nt < 4; ++nt)
        #pragma unroll
        for (int mt = 0; mt < 4; ++mt) acc[nt][mt] = z4;

    int aOff[4], bOff[4];
    #pragma unroll
    for (int mt = 0; mt < 4; ++mt) {
        const int Mrow = mq*64 + mt*16 + l15;       // = i_l*32 + c
        aOff[mt] = ((i0 + (Mrow >> 5)) * CH + (Mrow & 31)) * S_ + quad*8;
    }
    #pragma unroll
    for (int nt = 0; nt < 4; ++nt) {
        const int Ncol = nh*64 + nt*16 + l15;       // = j_l*32 + d
        bOff[nt] = ((j0 + (Ncol >> 5)) * CH + (Ncol & 31)) * S_ + quad*8;
    }

    #pragma unroll
    for (int kk = 0; kk < 4; ++kk) {
        bf16x8 af[4], bfr[4];
        #pragma unroll
        for (int mt = 0; mt < 4; ++mt) af[mt]  = *(const bf16x8*)&At[aOff[mt] + kk*32];
        #pragma unroll
        for (int nt = 0; nt < 4; ++nt) bfr[nt] = *(const bf16x8*)&Bt[bOff[nt] + kk*32];
        #pragma unroll
        for (int nt = 0; nt < 4; ++nt)
            #pragma unroll
            for (int mt = 0; mt < 4; ++mt)
                acc[nt][mt] = __builtin_amdgcn_mfma_f32_16x16x32_bf16(
                    bfr[nt], af[mt], acc[nt][mt], 0, 0, 0);
    }

    // ---- fused RN: p = wave*4+quad owns pair (i0+p>>2, j0+p&3) ----
    {
        const int p = wave*4 + quad;
        const int ic = i0 + (p >> 2), jc = j0 + (p & 3);
        float a = 0.f;
        #pragma unroll
        for (int u = 0; u < 8; ++u) {
            const int s = l15*8 + u;
            a += mask[s*N_ + ic] * mask[s*N_ + jc];
        }
        a += __shfl_xor(a, 1, 64);
        a += __shfl_xor(a, 2, 64);
        a += __shfl_xor(a, 4, 64);
        a += __shfl_xor(a, 8, 64);
        if (l15 == 0) RNl[p] = 1.0f / (a + 1e-3f);
    }

    // ---- O writes: col(l15)->(i_l,c); row(quad,r)->(j_l,d), r = consec d --
    #pragma unroll
    for (int mt = 0; mt < 4; ++mt) {
        const int Mcol = mq*64 + mt*16 + l15;
        const int i_l = Mcol >> 5, c = Mcol & 31;
        #pragma unroll
        for (int nt = 0; nt < 4; ++nt) {
            const int Nrow = nh*64 + nt*16 + quad*4;
            const int j_l = Nrow >> 5, d0 = Nrow & 31;
            const int p = i_l*4 + j_l;              // uniform per (mt,nt)
            pack4 pk;
            #pragma unroll
            for (int r = 0; r < 4; ++r) pk.h[r] = __float2bfloat16(acc[nt][mt][r]);
            *(uint2*)&O[p*OR + c*36 + d0] = pk.u;
        }
    }
    __syncthreads();

    // ---- stage 3: 32p x 16z per wave, K=1024, wf in two 16-frag chunks ----
    f32x4 oacc[2];
    oacc[0] = z4; oacc[1] = z4;
    #pragma unroll
    for (int h = 0; h < 2; ++h) {
        bf16x8 wf[16];
        #pragma unroll
        for (int k2 = 0; k2 < 16; ++k2)
            wf[k2] = *(const bf16x8*)&woutT[(size_t)(zb + l15) * (CH*CH)
                                            + (h*16 + k2)*32 + quad*8];
        #pragma unroll
        for (int k2 = 0; k2 < 16; ++k2) {
            const int kk = h*16 + k2;
            #pragma unroll
            for (int mt2 = 0; mt2 < 2; ++mt2) {
                const int row = mt2*16 + l15;
                bf16x8 a = *(const bf16x8*)&O[row*OR + kk*36 + quad*8];
                oacc[mt2] = __builtin_amdgcn_mfma_f32_16x16x32_bf16(
                    a, wf[k2], oacc[mt2], 0, 0, 0);
            }
        }
    }

    // ---- epilogue: col(l15)->z, row(quad,r)->p ----
    const float bz = bout[zb + l15];
    #pragma unroll
    for (int mt2 = 0; mt2 < 2; ++mt2) {
        #pragma unroll
        for (int r = 0; r < 4; ++r) {
            const int p = mt2*16 + quad*4 + r;
            const int i = i0 + (p >> 2), j = j0 + (p & 3);
            out[((size_t)(i*N_ + j))*CZ + zb + l15] = (oacc[mt2][r] + bz) * RNl[p];
        }
    }
}

extern "C" void kernel_launch(void* const* d_in, const int* in_sizes, int n_in,
                              void* d_out, int out_size, void* d_ws, size_t ws_size,
                              hipStream_t stream)
{
    const float* m    = (const float*)d_in[0];
    const float* mask = (const float*)d_in[1];
    const float* gam  = (const float*)d_in[2];
    const float* bet  = (const float*)d_in[3];
    const float* w1   = (const float*)d_in[4];
    const float* b1   = (const float*)d_in[5];
    const float* w2   = (const float*)d_in[6];
    const float* b2   = (const float*)d_in[7];
    const float* wout = (const float*)d_in[8];
    const float* bout = (const float*)d_in[9];
    float* out = (float*)d_out;

    __hip_bfloat16* At    = (__hip_bfloat16*)d_ws;                 // [N][CH][S]
    __hip_bfloat16* Bt    = At + (size_t)N_ * CH * S_;             // [N][CH][S]
    __hip_bfloat16* woutT = Bt + (size_t)N_ * CH * S_;             // [CZ][1024]
    __hip_bfloat16* wt12  = woutT + (size_t)CZ * CH * CH;          // [64][256]

    k_prep<<<192, 256, 0, stream>>>(w1, w2, wout, wt12, woutT);
    dim3 gl(24, 16);
    k_lnp<<<gl, 256, 0, stream>>>(m, mask, gam, bet, b1, b2, wt12, At, Bt);
    dim3 grid(N_ / 8, N_ / 4);
    k_opm<<<grid, 512, 0, stream>>>(At, Bt, mask, woutT, bout, out);
}

// Round 4
// 427.920 us; speedup vs baseline: 1.4268x; 1.0827x over previous
//
#include <hip/hip_runtime.h>
#include <hip/hip_bf16.h>

#define S_ 128
#define N_ 384
#define CM 256
#define CH 32
#define CZ 128

typedef __attribute__((ext_vector_type(8))) __bf16 bf16x8;
typedef __attribute__((ext_vector_type(4))) float f32x4;

union pack4 { __hip_bfloat16 h[4]; uint2 u; };

// ---- Kernel P: fused weight prep -----------------------------------------
__global__ __launch_bounds__(256) void k_prep(const float* __restrict__ w1,
                                              const float* __restrict__ w2,
                                              const float* __restrict__ wout,
                                              __hip_bfloat16* __restrict__ wt12,
                                              __hip_bfloat16* __restrict__ woutT)
{
    const int b = blockIdx.x, t = threadIdx.x;
    if (b < 64) {
        const float* w = (b < CH) ? w1 : w2;
        wt12[b * CM + t] = __float2bfloat16(w[(size_t)t * CH + (b & 31)]);
    } else {
        const int z = b - 64;
        for (int cd = t; cd < CH*CH; cd += 256)
            woutT[(size_t)z * (CH*CH) + cd] = __float2bfloat16(wout[(size_t)cd * CZ + z]);
    }
}

// ---- Kernel R: reciprocal norm (separate again: k_opm loads RN directly) --
__global__ __launch_bounds__(N_) void k_rnorm(const float* __restrict__ mask,
                                              float* __restrict__ RN)
{
    const int i = blockIdx.x, j = threadIdx.x;
    float acc = 0.f;
    #pragma unroll 8
    for (int s = 0; s < S_; ++s)
        acc += mask[s*N_ + i] * mask[s*N_ + j];
    RN[i*N_ + j] = 1.0f / (acc + 1e-3f);
}

// ---- Kernel 1: LayerNorm + dual projection via MFMA (unchanged) ----------
#define LNR 264
__global__ __launch_bounds__(256) void k_lnp(
    const float* __restrict__ m, const float* __restrict__ mask,
    const float* __restrict__ gamma, const float* __restrict__ beta,
    const float* __restrict__ b1, const float* __restrict__ b2,
    const __hip_bfloat16* __restrict__ wt12,
    __hip_bfloat16* __restrict__ At, __hip_bfloat16* __restrict__ Bt)
{
    __shared__ __hip_bfloat16 lnS[128 * LNR];
    __shared__ float msk[128];
    const int n0 = blockIdx.x * 16, s0 = blockIdx.y * 8;
    const int t = threadIdx.x, wave = t >> 6, lane = t & 63;
    const int l15 = lane & 15, quad = lane >> 4;

    if (t < 128) msk[t] = mask[(s0 + (t & 7))*N_ + n0 + (t >> 3)];

    float4 g  = ((const float4*)gamma)[lane];
    float4 be = ((const float4*)beta)[lane];
    for (int i = 0; i < 32; ++i) {
        const int row = wave*32 + i;
        const int n = row >> 3, s = row & 7;
        float4 x = ((const float4*)(m + ((size_t)((s0+s)*N_ + n0 + n)) * CM))[lane];
        float sum = x.x + x.y + x.z + x.w;
        float ssq = x.x*x.x + x.y*x.y + x.z*x.z + x.w*x.w;
        #pragma unroll
        for (int off = 32; off >= 1; off >>= 1) {
            sum += __shfl_xor(sum, off, 64);
            ssq += __shfl_xor(ssq, off, 64);
        }
        const float mean = sum * (1.0f/CM);
        const float var  = ssq * (1.0f/CM) - mean*mean;
        const float rstd = rsqrtf(var + 1e-5f);
        pack4 pk;
        pk.h[0] = __float2bfloat16((x.x - mean)*rstd*g.x + be.x);
        pk.h[1] = __float2bfloat16((x.y - mean)*rstd*g.y + be.y);
        pk.h[2] = __float2bfloat16((x.z - mean)*rstd*g.z + be.z);
        pk.h[3] = __float2bfloat16((x.w - mean)*rstd*g.w + be.w);
        *(uint2*)&lnS[row*LNR + lane*4] = pk.u;
    }
    __syncthreads();

    f32x4 acc[2][4];
    const f32x4 z4 = {0.f,0.f,0.f,0.f};
    #pragma unroll
    for (int mt = 0; mt < 2; ++mt)
        #pragma unroll
        for (int nt = 0; nt < 4; ++nt) acc[mt][nt] = z4;

    #pragma unroll
    for (int kk = 0; kk < 8; ++kk) {
        bf16x8 a0 = *(const bf16x8*)&lnS[(wave*32      + l15)*LNR + kk*32 + quad*8];
        bf16x8 a1 = *(const bf16x8*)&lnS[(wave*32 + 16 + l15)*LNR + kk*32 + quad*8];
        #pragma unroll
        for (int nt = 0; nt < 4; ++nt) {
            bf16x8 wv = *(const bf16x8*)&wt12[(size_t)(nt*16 + l15)*CM + kk*32 + quad*8];
            acc[0][nt] = __builtin_amdgcn_mfma_f32_16x16x32_bf16(a0, wv, acc[0][nt], 0,0,0);
            acc[1][nt] = __builtin_amdgcn_mfma_f32_16x16x32_bf16(a1, wv, acc[1][nt], 0,0,0);
        }
    }

    #pragma unroll
    for (int nt = 0; nt < 4; ++nt) {
        const int ncol = nt*16 + l15;
        const int sel = ncol >> 5, c = ncol & 31;
        const float bias = sel ? b2[c] : b1[c];
        __hip_bfloat16* dst = sel ? Bt : At;
        #pragma unroll
        for (int mt = 0; mt < 2; ++mt) {
            const int rowb = wave*32 + mt*16 + quad*4;
            const int n_loc = rowb >> 3, s_loc = rowb & 7;
            pack4 pk;
            #pragma unroll
            for (int r = 0; r < 4; ++r)
                pk.h[r] = __float2bfloat16((acc[mt][nt][r] + bias) * msk[rowb + r]);
            *(uint2*)&dst[((size_t)(n0 + n_loc)*CH + c)*S_ + s0 + s_loc] = pk.u;
        }
    }
}

// ---- Kernel 2: persistent pipelined outer-product + w_out GEMM -----------
// 256 blocks (1/CU) x 512 thr (8 waves, launch_bounds(512,2) -> 256 regs).
// Each block walks 18 tiles of 8i x 4j. Register budget (R2/R3 lessons:
// 4 waves/SIMD = 128 regs starves this kernel; at 256 it fits):
//   wf[32] persistent 128 + acc 64 (AGPR) + oacc 8 + addr ~24  ~= 224 < 256
// Double-buffered O (2 x 74.2 KB = 145 KB, R0's proven LDS size): tile t's
// stage-2 global loads overlap tile t-1's stage-3 LDS+MFMA; ONE barrier
// per tile (write buf[t&1] vs read buf[(t-1)&1] -> prev iter's barrier
// already ordered the conflicting buffer reuse).
// Tile walk is XCD-banded (R1 lesson): xcd = b&7 owns j-band of 12 j-blks;
// per-XCD L2 set = At 3.1 MB + Bt 0.38 MB + woutT 0.26 MB < 4 MB.
// out uses nontemporal stores so the 75 MB write stream doesn't evict it.
#define OR 1160
#define OSZ (32*OR)
#define NT 18

#define STAGE2_WRITE(I0, J0, BUF)                                          \
  {                                                                        \
    const int dA = (I0)*CH*S_, dB = (J0)*CH*S_;                            \
    f32x4 acc[4][4];                                                       \
    _Pragma("unroll") for (int nt = 0; nt < 4; ++nt)                       \
      _Pragma("unroll") for (int mt = 0; mt < 4; ++mt) acc[nt][mt] = z4;   \
    _Pragma("unroll") for (int kk = 0; kk < 4; ++kk) {                     \
      bf16x8 af[4], bfr[4];                                                \
      _Pragma("unroll") for (int mt = 0; mt < 4; ++mt)                     \
        af[mt] = *(const bf16x8*)&At[dA + aBase[mt] + kk*32];              \
      _Pragma("unroll") for (int nt = 0; nt < 4; ++nt)                     \
        bfr[nt] = *(const bf16x8*)&Bt[dB + bBase[nt] + kk*32];             \
      _Pragma("unroll") for (int nt = 0; nt < 4; ++nt)                     \
        _Pragma("unroll") for (int mt = 0; mt < 4; ++mt)                   \
          acc[nt][mt] = __builtin_amdgcn_mfma_f32_16x16x32_bf16(           \
              bfr[nt], af[mt], acc[nt][mt], 0, 0, 0);                      \
    }                                                                      \
    __hip_bfloat16* Ob = &O[(BUF)*OSZ];                                    \
    _Pragma("unroll") for (int mt = 0; mt < 4; ++mt) {                     \
      const int Mcol = mq*64 + mt*16 + l15;                                \
      const int i_l = Mcol >> 5, c = Mcol & 31;                            \
      _Pragma("unroll") for (int nt = 0; nt < 4; ++nt) {                   \
        const int Nrow = nh*64 + nt*16 + quad*4;                           \
        const int j_l = Nrow >> 5, d0 = Nrow & 31;                         \
        const int p = i_l*4 + j_l;                                         \
        pack4 pk;                                                          \
        _Pragma("unroll") for (int r = 0; r < 4; ++r)                      \
          pk.h[r] = __float2bfloat16(acc[nt][mt][r]);                      \
        *(uint2*)&Ob[p*OR + c*36 + d0] = pk.u;                             \
      }                                                                    \
    }                                                                      \
  }

#define STAGE3_OUT(PI0, PJ0, BUF)                                          \
  {                                                                        \
    const __hip_bfloat16* Op = &O[(BUF)*OSZ];                              \
    f32x4 oacc[2]; oacc[0] = z4; oacc[1] = z4;                             \
    _Pragma("unroll") for (int kk = 0; kk < 32; ++kk)                      \
      _Pragma("unroll") for (int mt2 = 0; mt2 < 2; ++mt2) {                \
        bf16x8 a = *(const bf16x8*)&Op[(mt2*16 + l15)*OR + kk*36 + quad*8];\
        oacc[mt2] = __builtin_amdgcn_mfma_f32_16x16x32_bf16(               \
            a, wf[kk], oacc[mt2], 0, 0, 0);                                \
      }                                                                    \
    _Pragma("unroll") for (int mt2 = 0; mt2 < 2; ++mt2)                    \
      _Pragma("unroll") for (int r = 0; r < 4; ++r) {                      \
        const int p = mt2*16 + quad*4 + r;                                 \
        const int i = (PI0) + (p >> 2), j = (PJ0) + (p & 3);               \
        __builtin_nontemporal_store((oacc[mt2][r] + bz) * RN[i*N_ + j],    \
            &out[((size_t)(i*N_ + j))*CZ + zb + l15]);                     \
      }                                                                    \
  }

__global__ __launch_bounds__(512, 2) void k_opm(
    const __hip_bfloat16* __restrict__ At, const __hip_bfloat16* __restrict__ Bt,
    const float* __restrict__ RN, const __hip_bfloat16* __restrict__ woutT,
    const float* __restrict__ bout, float* __restrict__ out)
{
    __shared__ __hip_bfloat16 O[2*OSZ];   // 145 KB (R0-proven size)
    const int t = threadIdx.x;
    const int wave = t >> 6, lane = t & 63;
    const int l15 = lane & 15, quad = lane >> 4;
    const int mq = wave & 3, nh = wave >> 2;
    const int zb = wave * 16;
    const f32x4 z4 = {0.f,0.f,0.f,0.f};

    // persistent per-wave 16-z woutT slice (128 VGPR, loaded ONCE per block)
    bf16x8 wf[32];
    #pragma unroll
    for (int kk = 0; kk < 32; ++kk)
        wf[kk] = *(const bf16x8*)&woutT[(size_t)(zb + l15)*(CH*CH) + kk*32 + quad*8];
    const float bz = bout[zb + l15];

    // tile-invariant per-lane offsets
    int aBase[4], bBase[4];
    #pragma unroll
    for (int mt = 0; mt < 4; ++mt) {
        const int Mrow = mq*64 + mt*16 + l15;           // = i_l*32 + c
        aBase[mt] = ((Mrow >> 5)*CH + (Mrow & 31))*S_ + quad*8;
    }
    #pragma unroll
    for (int nt = 0; nt < 4; ++nt) {
        const int Ncol = nh*64 + nt*16 + l15;           // = j_l*32 + d
        bBase[nt] = ((Ncol >> 5)*CH + (Ncol & 31))*S_ + quad*8;
    }

    // XCD-banded walk: xcd owns j_blk in [12*xcd, 12*xcd+12); within the
    // band, q sweeps i fastest (i-contiguous strips, j advances slowly).
    const int slot = blockIdx.x >> 3, xcd = blockIdx.x & 7;

    // prologue: tile 0 -> buf 0
    int q  = slot * NT;
    int i0 = (q % 48) * 8;
    int j0 = (xcd*12 + q/48) * 4;
    STAGE2_WRITE(i0, j0, 0)
    __syncthreads();
    int pi0 = i0, pj0 = j0;

    #pragma unroll 1
    for (int tl = 1; tl < NT; ++tl) {
        q  = slot * NT + tl;
        i0 = (q % 48) * 8;
        j0 = (xcd*12 + q/48) * 4;

        STAGE3_OUT(pi0, pj0, (tl-1)&1)     // consume prev tile (LDS+MFMA)
        STAGE2_WRITE(i0, j0, tl&1)         // produce cur tile (global+MFMA)
        __syncthreads();                   // orders buf reuse (1 barrier/tile)

        pi0 = i0; pj0 = j0;
    }
    // tail: finish last tile
    STAGE3_OUT(pi0, pj0, (NT-1)&1)
}

extern "C" void kernel_launch(void* const* d_in, const int* in_sizes, int n_in,
                              void* d_out, int out_size, void* d_ws, size_t ws_size,
                              hipStream_t stream)
{
    const float* m    = (const float*)d_in[0];
    const float* mask = (const float*)d_in[1];
    const float* gam  = (const float*)d_in[2];
    const float* bet  = (const float*)d_in[3];
    const float* w1   = (const float*)d_in[4];
    const float* b1   = (const float*)d_in[5];
    const float* w2   = (const float*)d_in[6];
    const float* b2   = (const float*)d_in[7];
    const float* wout = (const float*)d_in[8];
    const float* bout = (const float*)d_in[9];
    float* out = (float*)d_out;

    __hip_bfloat16* At    = (__hip_bfloat16*)d_ws;                 // [N][CH][S]
    __hip_bfloat16* Bt    = At + (size_t)N_ * CH * S_;             // [N][CH][S]
    __hip_bfloat16* woutT = Bt + (size_t)N_ * CH * S_;             // [CZ][1024]
    __hip_bfloat16* wt12  = woutT + (size_t)CZ * CH * CH;          // [64][256]
    float*          RN    = (float*)(wt12 + (size_t)64 * CM);      // [N][N]

    k_prep<<<192, 256, 0, stream>>>(w1, w2, wout, wt12, woutT);
    k_rnorm<<<N_, N_, 0, stream>>>(mask, RN);
    dim3 gl(24, 16);
    k_lnp<<<gl, 256, 0, stream>>>(m, mask, gam, bet, b1, b2, wt12, At, Bt);
    k_opm<<<256, 512, 0, stream>>>(At, Bt, RN, woutT, bout, out);
}

// Round 5
// 376.269 us; speedup vs baseline: 1.6227x; 1.1373x over previous
//
#include <hip/hip_runtime.h>
#include <hip/hip_bf16.h>

#define S_ 128
#define N_ 384
#define CM 256
#define CH 32
#define CZ 128

typedef __attribute__((ext_vector_type(8))) __bf16 bf16x8;
typedef __attribute__((ext_vector_type(4))) float f32x4;

union pack4 { __hip_bfloat16 h[4]; uint2 u; };

// ---- Kernel P: fused weight prep -----------------------------------------
__global__ __launch_bounds__(256) void k_prep(const float* __restrict__ w1,
                                              const float* __restrict__ w2,
                                              const float* __restrict__ wout,
                                              __hip_bfloat16* __restrict__ wt12,
                                              __hip_bfloat16* __restrict__ woutT)
{
    const int b = blockIdx.x, t = threadIdx.x;
    if (b < 64) {
        const float* w = (b < CH) ? w1 : w2;
        wt12[b * CM + t] = __float2bfloat16(w[(size_t)t * CH + (b & 31)]);
    } else {
        const int z = b - 64;
        for (int cd = t; cd < CH*CH; cd += 256)
            woutT[(size_t)z * (CH*CH) + cd] = __float2bfloat16(wout[(size_t)cd * CZ + z]);
    }
}

// ---- Kernel R: reciprocal norm -------------------------------------------
__global__ __launch_bounds__(N_) void k_rnorm(const float* __restrict__ mask,
                                              float* __restrict__ RN)
{
    const int i = blockIdx.x, j = threadIdx.x;
    float acc = 0.f;
    #pragma unroll 8
    for (int s = 0; s < S_; ++s)
        acc += mask[s*N_ + i] * mask[s*N_ + j];
    RN[i*N_ + j] = 1.0f / (acc + 1e-3f);
}

// ---- Kernel 1: LayerNorm + dual projection via MFMA (unchanged) ----------
#define LNR 264
__global__ __launch_bounds__(256) void k_lnp(
    const float* __restrict__ m, const float* __restrict__ mask,
    const float* __restrict__ gamma, const float* __restrict__ beta,
    const float* __restrict__ b1, const float* __restrict__ b2,
    const __hip_bfloat16* __restrict__ wt12,
    __hip_bfloat16* __restrict__ At, __hip_bfloat16* __restrict__ Bt)
{
    __shared__ __hip_bfloat16 lnS[128 * LNR];
    __shared__ float msk[128];
    const int n0 = blockIdx.x * 16, s0 = blockIdx.y * 8;
    const int t = threadIdx.x, wave = t >> 6, lane = t & 63;
    const int l15 = lane & 15, quad = lane >> 4;

    if (t < 128) msk[t] = mask[(s0 + (t & 7))*N_ + n0 + (t >> 3)];

    float4 g  = ((const float4*)gamma)[lane];
    float4 be = ((const float4*)beta)[lane];
    for (int i = 0; i < 32; ++i) {
        const int row = wave*32 + i;
        const int n = row >> 3, s = row & 7;
        float4 x = ((const float4*)(m + ((size_t)((s0+s)*N_ + n0 + n)) * CM))[lane];
        float sum = x.x + x.y + x.z + x.w;
        float ssq = x.x*x.x + x.y*x.y + x.z*x.z + x.w*x.w;
        #pragma unroll
        for (int off = 32; off >= 1; off >>= 1) {
            sum += __shfl_xor(sum, off, 64);
            ssq += __shfl_xor(ssq, off, 64);
        }
        const float mean = sum * (1.0f/CM);
        const float var  = ssq * (1.0f/CM) - mean*mean;
        const float rstd = rsqrtf(var + 1e-5f);
        pack4 pk;
        pk.h[0] = __float2bfloat16((x.x - mean)*rstd*g.x + be.x);
        pk.h[1] = __float2bfloat16((x.y - mean)*rstd*g.y + be.y);
        pk.h[2] = __float2bfloat16((x.z - mean)*rstd*g.z + be.z);
        pk.h[3] = __float2bfloat16((x.w - mean)*rstd*g.w + be.w);
        *(uint2*)&lnS[row*LNR + lane*4] = pk.u;
    }
    __syncthreads();

    f32x4 acc[2][4];
    const f32x4 z4 = {0.f,0.f,0.f,0.f};
    #pragma unroll
    for (int mt = 0; mt < 2; ++mt)
        #pragma unroll
        for (int nt = 0; nt < 4; ++nt) acc[mt][nt] = z4;

    #pragma unroll
    for (int kk = 0; kk < 8; ++kk) {
        bf16x8 a0 = *(const bf16x8*)&lnS[(wave*32      + l15)*LNR + kk*32 + quad*8];
        bf16x8 a1 = *(const bf16x8*)&lnS[(wave*32 + 16 + l15)*LNR + kk*32 + quad*8];
        #pragma unroll
        for (int nt = 0; nt < 4; ++nt) {
            bf16x8 wv = *(const bf16x8*)&wt12[(size_t)(nt*16 + l15)*CM + kk*32 + quad*8];
            acc[0][nt] = __builtin_amdgcn_mfma_f32_16x16x32_bf16(a0, wv, acc[0][nt], 0,0,0);
            acc[1][nt] = __builtin_amdgcn_mfma_f32_16x16x32_bf16(a1, wv, acc[1][nt], 0,0,0);
        }
    }

    #pragma unroll
    for (int nt = 0; nt < 4; ++nt) {
        const int ncol = nt*16 + l15;
        const int sel = ncol >> 5, c = ncol & 31;
        const float bias = sel ? b2[c] : b1[c];
        __hip_bfloat16* dst = sel ? Bt : At;
        #pragma unroll
        for (int mt = 0; mt < 2; ++mt) {
            const int rowb = wave*32 + mt*16 + quad*4;
            const int n_loc = rowb >> 3, s_loc = rowb & 7;
            pack4 pk;
            #pragma unroll
            for (int r = 0; r < 4; ++r)
                pk.h[r] = __float2bfloat16((acc[mt][nt][r] + bias) * msk[rowb + r]);
            *(uint2*)&dst[((size_t)(n0 + n_loc)*CH + c)*S_ + s0 + s_loc] = pk.u;
        }
    }
}

// ---- Kernel 2: fused MFMA outer-product + w_out GEMM ---------------------
// Block = 8i x 4j (32 p), 256 thr = 4 WAVES, LDS 74.2 KB -> 2 BLOCKS/CU,
// launch_bounds(256,2) -> 256 regs/thread. The overlap that R1/R3/R4 tried
// to build INSIDE a block comes free from two INDEPENDENT co-resident
// blocks: one block's stage-2 (VMEM latency) runs while the other's
// stage-3 (LDS+MFMA) runs -- no shared barrier between them.
// Register budget (R2/R3/R4 lessons): no persistent wf across phases.
//   stage 2: acc[4][8] 128 AGPR + 12 in-flight b128 loads ~48 + addr < 256
//   stage 3: wf[32] 128 (loaded after acc dies) + oacc 8 + O-reads  < 256
// Grid 48 x 96, bx = i fastest (R0-proven j-band L2 residency, FETCH ~15MB).
// Plain stores (R4: nontemporal cost ~25 MB write amplification).
#define OR 1160
__global__ __launch_bounds__(256, 2) void k_opm(
    const __hip_bfloat16* __restrict__ At, const __hip_bfloat16* __restrict__ Bt,
    const float* __restrict__ RN, const __hip_bfloat16* __restrict__ woutT,
    const float* __restrict__ bout, float* __restrict__ out)
{
    __shared__ __hip_bfloat16 O[32 * OR];   // 74.2 KB
    const int t = threadIdx.x;
    const int wave = t >> 6, lane = t & 63;
    const int l15 = lane & 15, quad = lane >> 4;
    const int mh = wave & 1, nh = wave >> 1;     // M-half x N-half
    const int i0 = blockIdx.x * 8, j0 = blockIdx.y * 4;
    const f32x4 z4 = {0.f,0.f,0.f,0.f};

    // ---- stage 2: M=256 (8i,32c) x N=128 (4j,32d), K=128 ----
    // wave tile = 128 x 64: acc[nt 4][mt 8]
    f32x4 acc[4][8];
    #pragma unroll
    for (int nt = 0; nt < 4; ++nt)
        #pragma unroll
        for (int mt = 0; mt < 8; ++mt) acc[nt][mt] = z4;

    int aOff[8], bOff[4];
    #pragma unroll
    for (int mt = 0; mt < 8; ++mt) {
        const int Mrow = mh*128 + mt*16 + l15;      // = i_l*32 + c
        aOff[mt] = ((i0 + (Mrow >> 5)) * CH + (Mrow & 31)) * S_ + quad*8;
    }
    #pragma unroll
    for (int nt = 0; nt < 4; ++nt) {
        const int Ncol = nh*64 + nt*16 + l15;       // = j_l*32 + d
        bOff[nt] = ((j0 + (Ncol >> 5)) * CH + (Ncol & 31)) * S_ + quad*8;
    }

    #pragma unroll
    for (int kk = 0; kk < 4; ++kk) {
        bf16x8 af[8], bfr[4];
        #pragma unroll
        for (int mt = 0; mt < 8; ++mt) af[mt]  = *(const bf16x8*)&At[aOff[mt] + kk*32];
        #pragma unroll
        for (int nt = 0; nt < 4; ++nt) bfr[nt] = *(const bf16x8*)&Bt[bOff[nt] + kk*32];
        #pragma unroll
        for (int nt = 0; nt < 4; ++nt)
            #pragma unroll
            for (int mt = 0; mt < 8; ++mt)
                acc[nt][mt] = __builtin_amdgcn_mfma_f32_16x16x32_bf16(
                    bfr[nt], af[mt], acc[nt][mt], 0, 0, 0);
    }

    // ---- O writes: col(l15)->(i_l,c); row(quad,r)->(j_l,d) ----
    #pragma unroll
    for (int mt = 0; mt < 8; ++mt) {
        const int Mcol = mh*128 + mt*16 + l15;
        const int i_l = Mcol >> 5, c = Mcol & 31;
        #pragma unroll
        for (int nt = 0; nt < 4; ++nt) {
            const int Nrow = nh*64 + nt*16 + quad*4;
            const int j_l = Nrow >> 5, d0 = Nrow & 31;
            const int p = i_l*4 + j_l;
            pack4 pk;
            #pragma unroll
            for (int r = 0; r < 4; ++r) pk.h[r] = __float2bfloat16(acc[nt][mt][r]);
            *(uint2*)&O[p*OR + c*36 + d0] = pk.u;
        }
    }
    __syncthreads();

    // ---- stage 3: wave owns 32 z as two 16-z chunks (wf loaded AFTER acc
    //      is dead -> no overlap of the two big register sets) ----
    const int zq = wave * 32;
    #pragma unroll
    for (int h = 0; h < 2; ++h) {
        const int zrow = zq + h*16 + l15;
        bf16x8 wf[32];
        #pragma unroll
        for (int kk = 0; kk < 32; ++kk)
            wf[kk] = *(const bf16x8*)&woutT[(size_t)zrow*(CH*CH) + kk*32 + quad*8];

        f32x4 oacc[2];
        oacc[0] = z4; oacc[1] = z4;
        #pragma unroll
        for (int kk = 0; kk < 32; ++kk) {
            #pragma unroll
            for (int mt2 = 0; mt2 < 2; ++mt2) {
                bf16x8 a = *(const bf16x8*)&O[(mt2*16 + l15)*OR + kk*36 + quad*8];
                oacc[mt2] = __builtin_amdgcn_mfma_f32_16x16x32_bf16(
                    a, wf[kk], oacc[mt2], 0, 0, 0);
            }
        }

        const float bz = bout[zrow];
        #pragma unroll
        for (int mt2 = 0; mt2 < 2; ++mt2) {
            #pragma unroll
            for (int r = 0; r < 4; ++r) {
                const int p = mt2*16 + quad*4 + r;
                const int i = i0 + (p >> 2), j = j0 + (p & 3);
                out[((size_t)(i*N_ + j))*CZ + zrow] = (oacc[mt2][r] + bz) * RN[i*N_ + j];
            }
        }
    }
}

extern "C" void kernel_launch(void* const* d_in, const int* in_sizes, int n_in,
                              void* d_out, int out_size, void* d_ws, size_t ws_size,
                              hipStream_t stream)
{
    const float* m    = (const float*)d_in[0];
    const float* mask = (const float*)d_in[1];
    const float* gam  = (const float*)d_in[2];
    const float* bet  = (const float*)d_in[3];
    const float* w1   = (const float*)d_in[4];
    const float* b1   = (const float*)d_in[5];
    const float* w2   = (const float*)d_in[6];
    const float* b2   = (const float*)d_in[7];
    const float* wout = (const float*)d_in[8];
    const float* bout = (const float*)d_in[9];
    float* out = (float*)d_out;

    __hip_bfloat16* At    = (__hip_bfloat16*)d_ws;                 // [N][CH][S]
    __hip_bfloat16* Bt    = At + (size_t)N_ * CH * S_;             // [N][CH][S]
    __hip_bfloat16* woutT = Bt + (size_t)N_ * CH * S_;             // [CZ][1024]
    __hip_bfloat16* wt12  = woutT + (size_t)CZ * CH * CH;          // [64][256]
    float*          RN    = (float*)(wt12 + (size_t)64 * CM);      // [N][N]

    k_prep<<<192, 256, 0, stream>>>(w1, w2, wout, wt12, woutT);
    k_rnorm<<<N_, N_, 0, stream>>>(mask, RN);
    dim3 gl(24, 16);
    k_lnp<<<gl, 256, 0, stream>>>(m, mask, gam, bet, b1, b2, wt12, At, Bt);
    dim3 grid(N_ / 8, N_ / 4);
    k_opm<<<grid, 256, 0, stream>>>(At, Bt, RN, woutT, bout, out);
}